// Round 3
// baseline (77.253 us; speedup 1.0000x reference)
//
#include <hip/hip_runtime.h>
#include <hip/hip_bf16.h>
#include <stdint.h>

#define B_ 4
#define M_ 4096
#define N_ 4096
#define D_ 256

typedef __attribute__((ext_vector_type(8))) short bf16x8;
typedef __attribute__((ext_vector_type(4))) float f32x4;

// RNE float->bf16 (no NaN in this data)
__device__ inline unsigned short f2bf(float f) {
    unsigned int u = __float_as_uint(f);
    return (unsigned short)((u + 0x7fffu + ((u >> 16) & 1u)) >> 16);
}

// One wave per row: compute 1/||row||, scale, convert to bf16.
__global__ __launch_bounds__(256) void norm_cvt(const float* __restrict__ x,
                                                const float* __restrict__ y,
                                                ushort* __restrict__ xb,
                                                ushort* __restrict__ yb) {
    int gw   = (blockIdx.x * 256 + threadIdx.x) >> 6;  // row id across both tensors
    int lane = threadIdx.x & 63;
    const int R = B_ * 4096;
    const float* src;
    ushort* dst;
    if (gw < R) { src = x + (size_t)gw * D_;        dst = xb + (size_t)gw * D_; }
    else        { src = y + (size_t)(gw - R) * D_;  dst = yb + (size_t)(gw - R) * D_; }

    float4 v = reinterpret_cast<const float4*>(src)[lane];   // 64 lanes * 4 = 256
    float ss = v.x * v.x + v.y * v.y + v.z * v.z + v.w * v.w;
#pragma unroll
    for (int off = 32; off; off >>= 1) ss += __shfl_xor(ss, off);
    float scale = ss > 0.f ? rsqrtf(ss) : 0.f;

    ushort4 o;
    o.x = f2bf(v.x * scale);
    o.y = f2bf(v.y * scale);
    o.z = f2bf(v.z * scale);
    o.w = f2bf(v.w * scale);
    reinterpret_cast<ushort4*>(dst)[lane] = o;
}

// C[b][m][n] = sum_d Yb[b][m][d] * Xb[b][n][d]   (both row-major = A*B^T GEMM)
// 128x128 tile, 4 waves (2x2 of 64x64), BK=32 double-buffered LDS (32 KiB ->
// 4 blocks/CU), global_load_lds(16B) staging with inverse-swizzled source,
// XOR-swizzled ds_reads (slot ^= (row>>1)&3), counted vmcnt(4) pipeline.
__global__ __launch_bounds__(256, 4) void cosgemm(const ushort* __restrict__ Xb,
                                                  const ushort* __restrict__ Yb,
                                                  float* __restrict__ out) {
    // LDS: [2 bufs][ A:128x32 | B:128x32 ] bf16 = 32 KiB
    __shared__ char smem[32768];

    const int tid  = threadIdx.x;
    const int w    = tid >> 6;
    const int lane = tid & 63;

    // XCD-aware bijective swizzle: 4096 blocks, 8 XCDs, 512 per XCD chunk
    int bid = blockIdx.x;
    int swz = ((bid & 7) << 9) | (bid >> 3);
    int b   = swz >> 10;          // batch
    int t   = swz & 1023;
    int tm  = (t >> 5) << 7;      // tile row base (y rows / output m)
    int tn  = (t & 31) << 7;      // tile col base (x rows / output n)

    const ushort* Ag = Yb + ((size_t)b * M_ + tm) * D_;
    const ushort* Bg = Xb + ((size_t)b * N_ + tn) * D_;

    // staging: chunk c (1 KiB) = rows 16c..16c+15 (16 rows x 64B) of 128x32 tile.
    // LDS dest linear (base + lane*16): lane -> row=c*16+(lane>>2), slot=lane&3.
    // Source slot pre-swizzled so LDS slot s of row r holds global slot
    // s ^ ((r>>1)&3)  [involution; read applies the same XOR].
    const int srow  = lane >> 2;                        // row within chunk
    const int gslot = (lane & 3) ^ ((lane >> 3) & 3);   // (l&3) ^ ((r>>1)&3)

    auto stage = [&](int buf, int k0) {
        char* base = smem + buf * 16384;
#pragma unroll
        for (int i = 0; i < 2; ++i) {
            int c = i * 4 + w;                 // 8 chunks over 4 waves
            const ushort* ga = Ag + (size_t)(c * 16 + srow) * D_ + k0 + gslot * 8;
            __builtin_amdgcn_global_load_lds(
                (const __attribute__((address_space(1))) void*)ga,
                (__attribute__((address_space(3))) void*)(base + c * 1024), 16, 0, 0);
            const ushort* gb = Bg + (size_t)(c * 16 + srow) * D_ + k0 + gslot * 8;
            __builtin_amdgcn_global_load_lds(
                (const __attribute__((address_space(1))) void*)gb,
                (__attribute__((address_space(3))) void*)(base + 8192 + c * 1024), 16, 0, 0);
        }
    };

    const int wr = (w >> 1) << 6;   // wave's 64-row block
    const int wc = (w & 1) << 6;    // wave's 64-col block

    f32x4 acc[4][4] = {};

    stage(0, 0);                    // 4 loads/wave in flight

#pragma unroll
    for (int s = 0; s < 8; ++s) {
        const int buf = s & 1;
        // barrier 1: all waves done READING buf[s^1] -> safe to overwrite.
        __builtin_amdgcn_s_barrier();
        if (s < 7) {
            stage(buf ^ 1, (s + 1) * 32);   // +4 loads/wave in flight
            // drain stage(s)'s 4 loads only; stage(s+1)'s 4 stay in flight
            asm volatile("s_waitcnt vmcnt(4)" ::: "memory");
        } else {
            asm volatile("s_waitcnt vmcnt(0)" ::: "memory");
        }
        // barrier 2: every wave's buf[s] complete -> tile ready
        __builtin_amdgcn_s_barrier();
        __builtin_amdgcn_sched_barrier(0);

        const char* Abase = smem + buf * 16384;
        const char* Bbase = Abase + 8192;
        // fragment: lane reads row (l&15), k-slot (l>>4); swizzled slot
        bf16x8 af[4], bfr[4];
#pragma unroll
        for (int m = 0; m < 4; ++m) {
            int row = wr + m * 16 + (lane & 15);
            int colb = (((lane >> 4) ^ ((row >> 1) & 3)) << 4);
            af[m] = *reinterpret_cast<const bf16x8*>(Abase + row * 64 + colb);
        }
#pragma unroll
        for (int n = 0; n < 4; ++n) {
            int row = wc + n * 16 + (lane & 15);
            int colb = (((lane >> 4) ^ ((row >> 1) & 3)) << 4);
            bfr[n] = *reinterpret_cast<const bf16x8*>(Bbase + row * 64 + colb);
        }
#pragma unroll
        for (int m = 0; m < 4; ++m)
#pragma unroll
            for (int n = 0; n < 4; ++n)
                acc[m][n] = __builtin_amdgcn_mfma_f32_16x16x32_bf16(
                    af[m], bfr[n], acc[m][n], 0, 0, 0);
    }

    // C/D layout: col = lane&15, row = (lane>>4)*4 + reg   [m89-verified]
    const int rj = (lane >> 4) << 2;
    const int cj = lane & 15;
#pragma unroll
    for (int m = 0; m < 4; ++m) {
#pragma unroll
        for (int j = 0; j < 4; ++j) {
            size_t r = (size_t)(tm + wr + m * 16 + rj + j);
            float* rowp = out + ((size_t)b * M_ + r) * N_ + tn + wc + cj;
#pragma unroll
            for (int n = 0; n < 4; ++n)
                rowp[n * 16] = acc[m][n][j];
        }
    }
}

extern "C" void kernel_launch(void* const* d_in, const int* in_sizes, int n_in,
                              void* d_out, int out_size, void* d_ws, size_t ws_size,
                              hipStream_t stream) {
    const float* x = (const float*)d_in[0];   // [4,4096,256] f32
    const float* y = (const float*)d_in[1];   // [4,4096,256] f32
    float* out = (float*)d_out;               // [4,4096,4096] f32

    ushort* xb = (ushort*)d_ws;                       // bf16 normalized x
    ushort* yb = xb + (size_t)B_ * N_ * D_;           // bf16 normalized y

    norm_cvt<<<8192, 256, 0, stream>>>(x, y, xb, yb); // 32768 rows, 4 waves/block
    cosgemm<<<4096, 256, 0, stream>>>(xb, yb, out);   // 4 batches * 32*32 tiles
}

// Round 4
// 72.544 us; speedup vs baseline: 1.0649x; 1.0649x over previous
//
#include <hip/hip_runtime.h>
#include <hip/hip_bf16.h>
#include <stdint.h>

#define B_ 4
#define M_ 4096
#define N_ 4096
#define D_ 256

typedef __attribute__((ext_vector_type(8))) short bf16x8;
typedef __attribute__((ext_vector_type(4))) float f32x4;

// RNE float->bf16 (no NaN in this data)
__device__ inline unsigned short f2bf(float f) {
    unsigned int u = __float_as_uint(f);
    return (unsigned short)((u + 0x7fffu + ((u >> 16) & 1u)) >> 16);
}

// One wave per row: compute 1/||row||, scale, convert to bf16.
__global__ __launch_bounds__(256) void norm_cvt(const float* __restrict__ x,
                                                const float* __restrict__ y,
                                                ushort* __restrict__ xb,
                                                ushort* __restrict__ yb) {
    int gw   = (blockIdx.x * 256 + threadIdx.x) >> 6;  // row id across both tensors
    int lane = threadIdx.x & 63;
    const int R = B_ * 4096;
    const float* src;
    ushort* dst;
    if (gw < R) { src = x + (size_t)gw * D_;        dst = xb + (size_t)gw * D_; }
    else        { src = y + (size_t)(gw - R) * D_;  dst = yb + (size_t)(gw - R) * D_; }

    float4 v = reinterpret_cast<const float4*>(src)[lane];   // 64 lanes * 4 = 256
    float ss = v.x * v.x + v.y * v.y + v.z * v.z + v.w * v.w;
#pragma unroll
    for (int off = 32; off; off >>= 1) ss += __shfl_xor(ss, off);
    float scale = ss > 0.f ? rsqrtf(ss) : 0.f;

    ushort4 o;
    o.x = f2bf(v.x * scale);
    o.y = f2bf(v.y * scale);
    o.z = f2bf(v.z * scale);
    o.w = f2bf(v.w * scale);
    reinterpret_cast<ushort4*>(dst)[lane] = o;
}

// C[b][m][n] = sum_d Yb[b][m][d] * Xb[b][n][d]   (A*B^T GEMM, A=Y rows, B=X rows)
// Each block: ONE 128-row band (tm) x FOUR 128-col tiles (tn0+q*128), q=0..3.
// K-pipeline (BK=64, 2 LDS bufs, counted vmcnt) runs across tile seams:
// 16 steps, one prologue, stores of quad q issued mid-loop (overlap compute).
__global__ __launch_bounds__(256, 2) void cosgemm(const ushort* __restrict__ Xb,
                                                  const ushort* __restrict__ Yb,
                                                  float* __restrict__ out) {
    // LDS: [2 bufs][ A:128x64 | B:128x64 ] bf16 = 64 KiB  -> 2 blocks/CU
    __shared__ char smem[65536];

    const int tid  = threadIdx.x;
    const int w    = tid >> 6;
    const int lane = tid & 63;

    // XCD-aware bijective swizzle: 1024 blocks, 8 XCDs, 128 per XCD chunk
    int bid = blockIdx.x;
    int swz = ((bid & 7) << 7) | (bid >> 3);
    int b   = swz >> 8;             // batch (0..3)
    int t   = swz & 255;
    int tm  = (t >> 3) << 7;        // 32 row-tiles
    int tn0 = (t & 7) << 9;         // 8 quad-cols * 512

    const ushort* Ag = Yb + ((size_t)b * M_ + tm) * D_;
    const ushort* Bg = Xb + ((size_t)b * N_ + tn0) * D_;

    // staging: chunk c (1 KiB) = rows 8c..8c+7 of a 128x64 tile.
    // LDS dest linear (base + lane*16); source slot pre-swizzled so LDS slot s
    // of row r holds global slot s ^ (r&7)  [involution; reads apply same XOR].
    const int srow  = lane >> 3;              // row within chunk (= row&7)
    const int gslot = (lane & 7) ^ srow;      // inverse-swizzled source slot

    // stage step s: A k-chunk (s&3)*64, B rows of quad (s>>2). 8 loads/thread.
    auto stage = [&](int buf, int s) {
        char* base = smem + buf * 32768;
        const int ka = (s & 3) * 64;
        const ushort* Bq = Bg + (size_t)(s >> 2) * 128 * D_;
#pragma unroll
        for (int i = 0; i < 4; ++i) {
            int c = i * 4 + w;                 // 16 chunks over 4 waves
            const ushort* ga = Ag + (size_t)(c * 8 + srow) * D_ + ka + gslot * 8;
            __builtin_amdgcn_global_load_lds(
                (const __attribute__((address_space(1))) void*)ga,
                (__attribute__((address_space(3))) void*)(base + c * 1024), 16, 0, 0);
            const ushort* gb = Bq + (size_t)(c * 8 + srow) * D_ + ka + gslot * 8;
            __builtin_amdgcn_global_load_lds(
                (const __attribute__((address_space(1))) void*)gb,
                (__attribute__((address_space(3))) void*)(base + 16384 + c * 1024), 16, 0, 0);
        }
    };

    const int wr = (w >> 1) << 6;   // wave's 64-row block
    const int wc = (w & 1) << 6;    // wave's 64-col block

    // one K-step of MFMA into acc (zero-init when zi)
    auto kstep = [&](f32x4 (&acc)[4][4], int buf, bool zi) {
        const char* Abase = smem + buf * 32768;
        const char* Bbase = Abase + 16384;
        if (zi) {
#pragma unroll
            for (int m = 0; m < 4; ++m)
#pragma unroll
                for (int n = 0; n < 4; ++n)
                    acc[m][n] = (f32x4){0.f, 0.f, 0.f, 0.f};
        }
#pragma unroll
        for (int ks = 0; ks < 2; ++ks) {
            const int colb = ((ks * 4 + (lane >> 4)) ^ (lane & 7)) << 4;
            bf16x8 af[4], bfr[4];
#pragma unroll
            for (int m = 0; m < 4; ++m) {
                int row = wr + m * 16 + (lane & 15);
                af[m] = *reinterpret_cast<const bf16x8*>(Abase + row * 128 + colb);
            }
#pragma unroll
            for (int n = 0; n < 4; ++n) {
                int row = wc + n * 16 + (lane & 15);
                bfr[n] = *reinterpret_cast<const bf16x8*>(Bbase + row * 128 + colb);
            }
#pragma unroll
            for (int m = 0; m < 4; ++m)
#pragma unroll
                for (int n = 0; n < 4; ++n)
                    acc[m][n] = __builtin_amdgcn_mfma_f32_16x16x32_bf16(
                        af[m], bfr[n], acc[m][n], 0, 0, 0);
        }
    };

    // C/D layout: col = lane&15, row = (lane>>4)*4 + reg   [m89-verified]
    auto store_tile = [&](f32x4 (&acc)[4][4], int tn) {
        const int rj = (lane >> 4) << 2;
        const int cj = lane & 15;
#pragma unroll
        for (int m = 0; m < 4; ++m) {
#pragma unroll
            for (int j = 0; j < 4; ++j) {
                size_t r = (size_t)(tm + wr + m * 16 + rj + j);
                float* rowp = out + ((size_t)b * M_ + r) * N_ + tn + wc + cj;
#pragma unroll
                for (int n = 0; n < 4; ++n)
                    rowp[n * 16] = acc[m][n][j];
            }
        }
    };

    f32x4 acc0[4][4], acc1[4][4];

    stage(0, 0);                    // 8 loads/wave-thread in flight

#pragma unroll
    for (int s = 0; s < 16; ++s) {
        const int buf = s & 1;
        // barrier 1: all waves done READING buf^1 -> safe to overwrite.
        __builtin_amdgcn_s_barrier();
        if (s < 15) {
            stage(buf ^ 1, s + 1);          // +8 loads in flight
            if (s >= 4 && (s & 3) == 0) {
                // queue: [stage(s)=8, stores=64, stage(s+1)=8] -> drain >=17
                asm volatile("s_waitcnt vmcnt(63)" ::: "memory");
            } else {
                // drain everything except stage(s+1)'s 8 (incl. store residue)
                asm volatile("s_waitcnt vmcnt(8)" ::: "memory");
            }
        } else {
            asm volatile("s_waitcnt vmcnt(0)" ::: "memory");
        }
        // barrier 2: every wave's buf[s] loads complete -> tile ready
        __builtin_amdgcn_s_barrier();
        __builtin_amdgcn_sched_barrier(0);

        const bool zi = (s & 3) == 0;
        if (((s >> 2) & 1) == 0) kstep(acc0, buf, zi);
        else                     kstep(acc1, buf, zi);

        if ((s & 3) == 3) {
            const int q = s >> 2;
            if ((q & 1) == 0) store_tile(acc0, tn0 + q * 128);
            else             store_tile(acc1, tn0 + q * 128);
        }
    }
}

extern "C" void kernel_launch(void* const* d_in, const int* in_sizes, int n_in,
                              void* d_out, int out_size, void* d_ws, size_t ws_size,
                              hipStream_t stream) {
    const float* x = (const float*)d_in[0];   // [4,4096,256] f32
    const float* y = (const float*)d_in[1];   // [4,4096,256] f32
    float* out = (float*)d_out;               // [4,4096,4096] f32

    ushort* xb = (ushort*)d_ws;                       // bf16 normalized x
    ushort* yb = xb + (size_t)B_ * N_ * D_;           // bf16 normalized y

    norm_cvt<<<8192, 256, 0, stream>>>(x, y, xb, yb); // 32768 rows, 4 waves/block
    cosgemm<<<1024, 256, 0, stream>>>(xb, yb, out);   // 4 batches * 32 * 8 quad-tiles
}